// Round 9
// baseline (219.222 us; speedup 1.0000x reference)
//
#include <hip/hip_runtime.h>
#include <hip/hip_bf16.h>

// Problem constants
#define Bn 32
#define Cn 32
#define Ln 512
#define INTRA 1024
#define INTER 256
#define DCP 64
#define DDE 512
#define SCALEF 0.05f

typedef __attribute__((ext_vector_type(8))) short short8;
typedef __attribute__((ext_vector_type(4))) float floatx4;

__device__ __forceinline__ short bf16_of(float f) {
    union { float f; unsigned u; } v; v.f = f;
    unsigned r = (v.u + 0x7FFFu + ((v.u >> 16) & 1u)) >> 16;
    return (short)r;
}
__device__ __forceinline__ float f_of_bf16(short h) {
    union { unsigned u; float f; } v;
    v.u = ((unsigned)(unsigned short)h) << 16;
    return v.f;
}
__device__ __forceinline__ short8 cvt8(float4 a, float4 b) {
    short8 r;
    r[0] = bf16_of(a.x); r[1] = bf16_of(a.y); r[2] = bf16_of(a.z); r[3] = bf16_of(a.w);
    r[4] = bf16_of(b.x); r[5] = bf16_of(b.y); r[6] = bf16_of(b.z); r[7] = bf16_of(b.w);
    return r;
}

// ---------------------------------------------------------------------------
// prep: dW1/dW2 fp32 -> bf16 (row-major [m][k] preserved). 8 els/thread.
// ---------------------------------------------------------------------------
__global__ __launch_bounds__(256) void prep_weights(
    const float* __restrict__ dW1, const float* __restrict__ dW2,
    short* __restrict__ dW1b, short* __restrict__ dW2b)
{
    const int i = (blockIdx.x * 256 + threadIdx.x) * 8;
    if (i < DDE * INTRA) {
        float4 x0 = *(const float4*)(dW1 + i), x1 = *(const float4*)(dW1 + i + 4);
        *(short8*)(dW1b + i) = cvt8(x0, x1);
        x0 = *(const float4*)(dW2 + i); x1 = *(const float4*)(dW2 + i + 4);
        *(short8*)(dW2b + i) = cvt8(x0, x1);
    }
}

// ---------------------------------------------------------------------------
// compress (r6-verified): T = relu(tile @ cW1^T + cb1); M1 = T @ cW2^T + cb2.
// BK=64. Grid (16,32)=512 blocks. Output M1T[c][d][i] bf16.
// ---------------------------------------------------------------------------
__global__ __launch_bounds__(256) void compress_fused(
    const float* __restrict__ map_raw, const float* __restrict__ cW1,
    const float* __restrict__ cb1, const float* __restrict__ cW2,
    const float* __restrict__ cb2, short* __restrict__ M1T)
{
    const int c  = blockIdx.y;
    const int m0 = blockIdx.x * 64;
    const float* A = map_raw + ((long)c * INTRA + m0) * INTER;

    __shared__ short Asb[64 * 72];
    __shared__ short Bsb[64 * 72];
    __shared__ short Tsb[64 * 72];

    const int t = threadIdx.x, w = t >> 6, lane = t & 63;
    const int ln = lane & 15, quad = lane >> 4;
    const int sr = t >> 2, sk = (t & 3) * 16;

    const float* ap = A + sr * INTER + sk;
    const float* bp = cW1 + sr * INTER + sk;

    floatx4 acc[4] = {};
    float4 a0 = *(const float4*)(ap),     a1 = *(const float4*)(ap + 4);
    float4 a2 = *(const float4*)(ap + 8), a3 = *(const float4*)(ap + 12);
    float4 b0 = *(const float4*)(bp),     b1 = *(const float4*)(bp + 4);
    float4 b2 = *(const float4*)(bp + 8), b3 = *(const float4*)(bp + 12);

    for (int k0 = 0; k0 < INTER; k0 += 64) {
        __syncthreads();
        *(short8*)&Asb[sr * 72 + sk]     = cvt8(a0, a1);
        *(short8*)&Asb[sr * 72 + sk + 8] = cvt8(a2, a3);
        *(short8*)&Bsb[sr * 72 + sk]     = cvt8(b0, b1);
        *(short8*)&Bsb[sr * 72 + sk + 8] = cvt8(b2, b3);
        __syncthreads();
        const int kn = k0 + 64;
        if (kn < INTER) {
            a0 = *(const float4*)(ap + kn);     a1 = *(const float4*)(ap + kn + 4);
            a2 = *(const float4*)(ap + kn + 8); a3 = *(const float4*)(ap + kn + 12);
            b0 = *(const float4*)(bp + kn);     b1 = *(const float4*)(bp + kn + 4);
            b2 = *(const float4*)(bp + kn + 8); b3 = *(const float4*)(bp + kn + 12);
        }
        #pragma unroll
        for (int kc = 0; kc < 2; ++kc) {
            short8 af = *(const short8*)&Asb[(w * 16 + ln) * 72 + kc * 32 + quad * 8];
            #pragma unroll
            for (int nt = 0; nt < 4; ++nt) {
                short8 bf = *(const short8*)&Bsb[(nt * 16 + ln) * 72 + kc * 32 + quad * 8];
                acc[nt] = __builtin_amdgcn_mfma_f32_16x16x32_bf16(af, bf, acc[nt], 0, 0, 0);
            }
        }
    }
    __syncthreads();

    #pragma unroll
    for (int nt = 0; nt < 4; ++nt) {
        const int n = nt * 16 + ln;
        const float b = cb1[n];
        #pragma unroll
        for (int r = 0; r < 4; ++r)
            Tsb[(w * 16 + quad * 4 + r) * 72 + n] = bf16_of(fmaxf(acc[nt][r] + b, 0.f));
    }
    __syncthreads();

    floatx4 acc2[4] = {};
    #pragma unroll
    for (int ks = 0; ks < 2; ++ks) {
        short8 af = *(const short8*)&Tsb[(w * 16 + ln) * 72 + ks * 32 + quad * 8];
        #pragma unroll
        for (int nt = 0; nt < 4; ++nt) {
            const float* wp = cW2 + (nt * 16 + ln) * 64 + ks * 32 + quad * 8;
            short8 bf = cvt8(*(const float4*)wp, *(const float4*)(wp + 4));
            acc2[nt] = __builtin_amdgcn_mfma_f32_16x16x32_bf16(af, bf, acc2[nt], 0, 0, 0);
        }
    }

    short* outp = M1T + (long)c * 64 * INTRA;
    #pragma unroll
    for (int nt = 0; nt < 4; ++nt) {
        const int n = nt * 16 + ln;
        const float b = cb2[n];
        short t0 = bf16_of(acc2[nt][0] + b);
        short t1 = bf16_of(acc2[nt][1] + b);
        short t2 = bf16_of(acc2[nt][2] + b);
        short t3 = bf16_of(acc2[nt][3] + b);
        *(short4*)(outp + (long)n * INTRA + m0 + w * 16 + quad * 4) =
            make_short4(t0, t1, t2, t3);
    }
}

// ---------------------------------------------------------------------------
// dn12: fused denoise-1 + denoise-2 per (channel, i-quarter).
// 128 blocks x 1024 threads (16 waves, one block/CU on 128 CUs).
// Phase A: full H[c] = relu(dW1 @ M1[c] + db1) -> private HTp[bid][d][h].
// Phase B: S16[c][i][d] for this block's 256 i's, K=512 over h.
// Only __syncthreads between phases — no grid-wide dependency.
// ---------------------------------------------------------------------------
__global__ __launch_bounds__(1024) void dn12(
    const short* __restrict__ dW1b, const short* __restrict__ dW2b,
    const short* __restrict__ M1T,
    const float* __restrict__ db1, const float* __restrict__ db2,
    short* __restrict__ HTp, short* __restrict__ S16)
{
    const int bid = blockIdx.x;      // 0..127
    const int c   = bid >> 2;
    const int iq  = bid & 3;

    __shared__ __align__(16) short arena[26112];   // 52,224 B

    const int t = threadIdx.x;       // 0..1023
    const int w = t >> 6;            // 0..15
    const int lane = t & 63;
    const int ln = lane & 15, quad = lane >> 4;
    const int dt = w & 3;            // d-tile 0..3
    const int tp = (w >> 2) * 2;     // m/n tile-pair base (0,2,4,6)

    short* Hme = HTp + (long)bid * 64 * DDE;   // private [d][h]

    // ---------------- Phase A: dn1 (full H[c]) ----------------
    {
        short* Asb = arena;              // [128][136] rows = h-local
        short* Bsb = arena + 17408;      // [64][136]  rows = d
        const int ar = t >> 3, ak = (t & 7) * 16;    // A: 16 shorts/thr
        const int br = t >> 4, bk = (t & 15) * 8;    // B: 8 shorts/thr
        const short* Bp = M1T + (long)c * 64 * INTRA + (long)br * INTRA + bk;

        for (int hs = 0; hs < 4; ++hs) {
            const int hb = hs * 128;
            const short* Ap = dW1b + (long)(hb + ar) * INTRA + ak;
            floatx4 acc[2] = {};
            short8 a0 = *(const short8*)(Ap);
            short8 a1 = *(const short8*)(Ap + 8);
            short8 b0 = *(const short8*)(Bp);

            for (int k0 = 0; k0 < INTRA; k0 += 128) {
                __syncthreads();
                *(short8*)&Asb[ar * 136 + ak]     = a0;
                *(short8*)&Asb[ar * 136 + ak + 8] = a1;
                *(short8*)&Bsb[br * 136 + bk]     = b0;
                __syncthreads();
                const int kn = k0 + 128;
                if (kn < INTRA) {
                    a0 = *(const short8*)(Ap + kn);
                    a1 = *(const short8*)(Ap + kn + 8);
                    b0 = *(const short8*)(Bp + kn);
                }
                #pragma unroll
                for (int kc = 0; kc < 4; ++kc) {
                    short8 bf = *(const short8*)&Bsb[(dt * 16 + ln) * 136 + kc * 32 + quad * 8];
                    #pragma unroll
                    for (int j = 0; j < 2; ++j) {
                        short8 af = *(const short8*)&Asb[((tp + j) * 16 + ln) * 136 + kc * 32 + quad * 8];
                        acc[j] = __builtin_amdgcn_mfma_f32_16x16x32_bf16(af, bf, acc[j], 0, 0, 0);
                    }
                }
            }
            // C[m=h][n=d]: h = hb + (tp+j)*16 + quad*4 + r ; d = dt*16 + ln
            #pragma unroll
            for (int j = 0; j < 2; ++j) {
                const int hrow = hb + (tp + j) * 16 + quad * 4;
                const int d    = dt * 16 + ln;
                float v0 = fmaxf(acc[j][0] + db1[hrow + 0], 0.f);
                float v1 = fmaxf(acc[j][1] + db1[hrow + 1], 0.f);
                float v2 = fmaxf(acc[j][2] + db1[hrow + 2], 0.f);
                float v3 = fmaxf(acc[j][3] + db1[hrow + 3], 0.f);
                *(short4*)(Hme + (long)d * DDE + hrow) =
                    make_short4(bf16_of(v0), bf16_of(v1), bf16_of(v2), bf16_of(v3));
            }
        }
    }
    __threadfence();
    __syncthreads();

    // ---------------- Phase B: dn2 (this block's 256 i's) ----------------
    {
        short* Asb = arena;              // [64][136]  rows = d (from H)
        short* Bsb = arena + 8704;       // [128][136] rows = i-local
        const int ar = t >> 4, ak = (t & 15) * 8;    // A: 8 shorts/thr
        const int br = t >> 3, bk = (t & 7) * 16;    // B: 16 shorts/thr
        const short* Ap = Hme + (long)ar * DDE + ak;

        for (int is = 0; is < 2; ++is) {
            const int ib = iq * 256 + is * 128;
            const short* Bp = dW2b + (long)(ib + br) * DDE + bk;
            floatx4 acc[2] = {};
            short8 a0 = *(const short8*)(Ap);
            short8 b0 = *(const short8*)(Bp);
            short8 b1 = *(const short8*)(Bp + 8);

            for (int k0 = 0; k0 < DDE; k0 += 128) {
                __syncthreads();
                *(short8*)&Asb[ar * 136 + ak]     = a0;
                *(short8*)&Bsb[br * 136 + bk]     = b0;
                *(short8*)&Bsb[br * 136 + bk + 8] = b1;
                __syncthreads();
                const int kn = k0 + 128;
                if (kn < DDE) {
                    a0 = *(const short8*)(Ap + kn);
                    b0 = *(const short8*)(Bp + kn);
                    b1 = *(const short8*)(Bp + kn + 8);
                }
                #pragma unroll
                for (int kc = 0; kc < 4; ++kc) {
                    short8 af = *(const short8*)&Asb[(dt * 16 + ln) * 136 + kc * 32 + quad * 8];
                    #pragma unroll
                    for (int j = 0; j < 2; ++j) {
                        short8 bf = *(const short8*)&Bsb[((tp + j) * 16 + ln) * 136 + kc * 32 + quad * 8];
                        acc[j] = __builtin_amdgcn_mfma_f32_16x16x32_bf16(af, bf, acc[j], 0, 0, 0);
                    }
                }
            }
            // C[m=d][n=i]: d = dt*16 + quad*4 + r ; i = ib + (tp+j)*16 + ln
            const int d0 = dt * 16 + quad * 4;
            #pragma unroll
            for (int j = 0; j < 2; ++j) {
                const int i = ib + (tp + j) * 16 + ln;
                const float bb = db2[i];
                short t0 = bf16_of(acc[j][0] + bb);
                short t1 = bf16_of(acc[j][1] + bb);
                short t2 = bf16_of(acc[j][2] + bb);
                short t3 = bf16_of(acc[j][3] + bb);
                *(short4*)(S16 + ((long)c * INTRA + i) * DCP + d0) =
                    make_short4(t0, t1, t2, t3);
            }
        }
    }
}

// ---------------------------------------------------------------------------
// fuse (r4/r6-verified): gather + L1-score + softmax + MFMA matvec + blend.
// ---------------------------------------------------------------------------
__global__ __launch_bounds__(256) void fuse_kernel(
    const float* __restrict__ x_loc, const int* __restrict__ indices,
    const short* __restrict__ S16, const float* __restrict__ lamda1,
    const float* __restrict__ lamda2, float* __restrict__ out)
{
    const int c = blockIdx.x;
    const int b = blockIdx.y;

    __shared__ float xs[Ln];
    __shared__ int   idx[Ln];
    __shared__ float red[4][DCP];
    __shared__ short wbf[DCP];
    __shared__ float ob[Ln];

    const int t = threadIdx.x;
    const float* xp = x_loc + ((long)b * Cn + c) * Ln;
    const int*   ip = indices + (long)b * Ln;
    ((float2*)xs)[t] = ((const float2*)xp)[t];
    ((int2*)idx)[t]  = ((const int2*)ip)[t];
    __syncthreads();

    const short* Sc = S16 + (long)c * INTRA * DCP;
    const int lane = t & 63;
    const int w    = t >> 6;
    const int r    = lane >> 4;
    const int dg   = lane & 15;

    float s0 = 0.f, s1 = 0.f, s2 = 0.f, s3 = 0.f;
    #pragma unroll 4
    for (int i = 0; i < 32; ++i) {
        const int lbase = w * 128 + i * 4;
        const int row   = idx[lbase + r];
        short4 g = *(const short4*)(Sc + (long)row * DCP + dg * 4);
        const float x = xs[lbase + r];
        s0 += fabsf(x - f_of_bf16(g.x));
        s1 += fabsf(x - f_of_bf16(g.y));
        s2 += fabsf(x - f_of_bf16(g.z));
        s3 += fabsf(x - f_of_bf16(g.w));
    }
    s0 += __shfl_xor(s0, 16); s0 += __shfl_xor(s0, 32);
    s1 += __shfl_xor(s1, 16); s1 += __shfl_xor(s1, 32);
    s2 += __shfl_xor(s2, 16); s2 += __shfl_xor(s2, 32);
    s3 += __shfl_xor(s3, 16); s3 += __shfl_xor(s3, 32);
    if (lane < 16) {
        red[w][dg * 4 + 0] = s0;
        red[w][dg * 4 + 1] = s1;
        red[w][dg * 4 + 2] = s2;
        red[w][dg * 4 + 3] = s3;
    }
    __syncthreads();

    if (t < DCP) {
        float sc = red[0][t] + red[1][t] + red[2][t] + red[3][t];
        sc = -sc * (SCALEF * 0.044194173824159216f);
        float m = sc;
        #pragma unroll
        for (int o = 32; o > 0; o >>= 1) m = fmaxf(m, __shfl_xor(m, o));
        float e = __expf(sc - m);
        float ssum = e;
        #pragma unroll
        for (int o = 32; o > 0; o >>= 1) ssum += __shfl_xor(ssum, o);
        wbf[t] = bf16_of(e / ssum);
    }
    __syncthreads();

    const int quad = lane >> 4;
    const int ln16 = lane & 15;
    short8 bw0 = *(const short8*)&wbf[quad * 8];
    short8 bw1 = *(const short8*)&wbf[32 + quad * 8];

    #pragma unroll
    for (int mt = 0; mt < 8; ++mt) {
        const int mrow = w * 128 + mt * 16 + ln16;
        const short* rp = Sc + (long)idx[mrow] * DCP;
        short8 a0 = *(const short8*)(rp + quad * 8);
        short8 a1 = *(const short8*)(rp + 32 + quad * 8);
        floatx4 acc = {};
        acc = __builtin_amdgcn_mfma_f32_16x16x32_bf16(a0, bw0, acc, 0, 0, 0);
        acc = __builtin_amdgcn_mfma_f32_16x16x32_bf16(a1, bw1, acc, 0, 0, 0);
        if (ln16 == 0) {
            const int l0 = w * 128 + mt * 16 + quad * 4;
            ob[l0 + 0] = acc[0];
            ob[l0 + 1] = acc[1];
            ob[l0 + 2] = acc[2];
            ob[l0 + 3] = acc[3];
        }
    }
    __syncthreads();

    const float lam1 = 1.f / (1.f + __expf(-lamda1[c]));
    #pragma unroll
    for (int j = 0; j < 2; ++j) {
        const int l = t + j * 256;
        const float lam = lam1 * (1.f / (1.f + __expf(-lamda2[l])));
        out[((long)b * Cn + c) * Ln + l] = ob[l] * lam + xs[l] * (1.f - lam);
    }
}

// ---------------------------------------------------------------------------
// Launch: prep, compress, dn12, fuse.
// ---------------------------------------------------------------------------
extern "C" void kernel_launch(void* const* d_in, const int* in_sizes, int n_in,
                              void* d_out, int out_size, void* d_ws, size_t ws_size,
                              hipStream_t stream)
{
    const float* x_loc   = (const float*)d_in[0];
    const int*   indices = (const int*)d_in[1];
    const float* map_raw = (const float*)d_in[2];
    const float* cW1     = (const float*)d_in[3];
    const float* cb1     = (const float*)d_in[4];
    const float* cW2     = (const float*)d_in[5];
    const float* cb2     = (const float*)d_in[6];
    const float* dW1     = (const float*)d_in[7];
    const float* db1     = (const float*)d_in[8];
    const float* dW2     = (const float*)d_in[9];
    const float* db2     = (const float*)d_in[10];
    const float* lamda1  = (const float*)d_in[11];
    const float* lamda2  = (const float*)d_in[12];
    float* out = (float*)d_out;

    short* wsS  = (short*)d_ws;
    short* M1T  = wsS;                    // 32*64*1024      = 2,097,152
    short* dW1b = M1T + 2097152;          // 512*1024        =   524,288
    short* dW2b = dW1b + 524288;          // 1024*512        =   524,288
    short* HTp  = dW2b + 524288;          // 128*64*512      = 4,194,304
    short* S16  = HTp + 4194304;          // 32*1024*64      = 2,097,152

    prep_weights<<<256, 256, 0, stream>>>(dW1, dW2, dW1b, dW2b);

    compress_fused<<<dim3(INTRA / 64, Cn), 256, 0, stream>>>(
        map_raw, cW1, cb1, cW2, cb2, M1T);

    dn12<<<128, 1024, 0, stream>>>(dW1b, dW2b, M1T, db1, db2, HTp, S16);

    fuse_kernel<<<dim3(Cn, Bn), 256, 0, stream>>>(
        x_loc, indices, S16, lamda1, lamda2, out);
}